// Round 5
// baseline (194.789 us; speedup 1.0000x reference)
//
#include <hip/hip_runtime.h>
#include <stdint.h>

typedef unsigned short u16;
typedef __attribute__((ext_vector_type(8))) short short8;
typedef __attribute__((ext_vector_type(4))) float floatx4;
typedef __attribute__((ext_vector_type(4))) u16 ushort4v;

typedef __attribute__((address_space(1))) const uint32_t gu32;
typedef __attribute__((address_space(3))) uint32_t lu32;

#define MFMA(a, b, c) __builtin_amdgcn_mfma_f32_16x16x32_bf16((a), (b), (c), 0, 0, 0)

__device__ __forceinline__ u16 f2bf(float f) {
    union { float f; uint32_t u; } x; x.f = f;
    uint32_t u = x.u;
    u += 0x7fffu + ((u >> 16) & 1u);
    return (u16)(u >> 16);
}

// packed f32x2 -> bf16x2 (RNE), single instruction (T12 primitive)
__device__ __forceinline__ uint32_t cvtpk_bf16(float lo, float hi) {
    uint32_t r;
    asm("v_cvt_pk_bf16_f32 %0, %1, %2" : "=v"(r) : "v"(lo), "v"(hi));
    return r;
}

// hardware exp2 (v_exp_f32 IS exp2)
__device__ __forceinline__ float fexp2(float x) {
#if defined(__has_builtin)
#if __has_builtin(__builtin_amdgcn_exp2f)
    return __builtin_amdgcn_exp2f(x);
#else
    return exp2f(x);
#endif
#else
    return exp2f(x);
#endif
}

// async global->LDS DMA, 16B per lane; lds base must be wave-uniform,
// HW scatters to base + lane*16 (m104/m108).
__device__ __forceinline__ void async16(u16* lds, const u16* g) {
    __builtin_amdgcn_global_load_lds((gu32*)g, (lu32*)lds, 16, 0, 0);
}

// K/V LDS tiles (attn): [64 rows][128 B], XOR-swizzled: byte ^= (row&7)<<4.
#define KV8(buf, row, byteInRow) \
    (*(short8*)((char*)(buf) + (((row) << 7) + ((byteInRow) ^ (((row) & 7) << 4)))))

// 0.125 (1/sqrt(64)) * log2(e): folded into Q so softmax runs in exp2 domain.
#define Q_SCALE_LOG2E 0.18033688011112042f

// ---------------------------------------------------------------------------
// prep: z=0..3 transpose W_z [k][n] fp32 -> WT [n][k] bf16; z=4 convert x.
// ---------------------------------------------------------------------------
__global__ __launch_bounds__(256) void prep_kernel(
    const float* __restrict__ x,
    const float* __restrict__ W0, const float* __restrict__ W1,
    const float* __restrict__ W2, const float* __restrict__ W3,
    u16* __restrict__ WT, u16* __restrict__ Xbf)
{
    const int z = blockIdx.z;
    const int tx = threadIdx.x, ty = threadIdx.y;
    if (z == 4) {
        const int bid = blockIdx.y * 32 + blockIdx.x;
        const int t = ty * 32 + tx;
        const size_t base = ((size_t)bid * 256 + t) * 16;
        const float* xf = x + base;
        short8 v0, v1;
#pragma unroll
        for (int j = 0; j < 8; j++) v0[j] = (short)f2bf(xf[j]);
#pragma unroll
        for (int j = 0; j < 8; j++) v1[j] = (short)f2bf(xf[8 + j]);
        *(short8*)&Xbf[base] = v0;
        *(short8*)&Xbf[base + 8] = v1;
        return;
    }
    __shared__ u16 tile[32][33];
    const float* W = (z == 0) ? W0 : (z == 1) ? W1 : (z == 2) ? W2 : W3;
    u16* dst = WT + (size_t)z * 1024 * 1024;
    const int n0 = blockIdx.x * 32, k0 = blockIdx.y * 32;
#pragma unroll
    for (int i = 0; i < 4; i++)
        tile[ty + i * 8][tx] = f2bf(W[(size_t)(k0 + ty + i * 8) * 1024 + n0 + tx]);
    __syncthreads();
#pragma unroll
    for (int i = 0; i < 4; i++)
        dst[(size_t)(n0 + ty + i * 8) * 1024 + k0 + tx] = tile[tx][ty + i * 8];
}

// ---------------------------------------------------------------------------
// QKV GEMM, 256x256 tile, 8 waves (2M x 4N), BK=32, ring-4 counted vmcnt.
// Wave tile 128x64 -> acc[8][4], 32 MFMA/wave/K-step.
// LDS: A[256][32] + B[256][32] per buffer (16+16 KB) x 4 = 128 KB.
// T2 swizzle: logical (row, byte cb) stored at byte cb ^ ((row&3)<<4);
// gload_lds dest stays LINEAR, global SOURCE col is inverse-swizzled
// (rule 21), ds_read applies the same XOR. 8-way -> 4-way conflict.
// vmcnt skeleton identical to round-4 ring (4 loads/wave/step):
// prologue 12 outstanding; loop vmcnt(8); tail 8 -> 4 -> 0. Buffer (t-1)&3
// is restaged only after barrier t, when all waves' tile-(t-1) ds_reads are
// complete (their MFMAs lgkm-waited before they entered barrier t).
// ---------------------------------------------------------------------------
__global__ __launch_bounds__(512, 2) void gemm_qkv_kernel(
    const u16* __restrict__ X, const u16* __restrict__ WT,
    u16* __restrict__ Q, u16* __restrict__ Kout, u16* __restrict__ VT)
{
    __shared__ __align__(16) u16 As[4][256 * 32];
    __shared__ __align__(16) u16 Bs[4][256 * 32];
    const int bid = blockIdx.x;        // 192 blocks
    const int xcd = bid & 7;
    const int idx = bid >> 3;          // 0..23
    const int rr  = idx & 1;           // m-tile within this XCD's stripe
    const int nn  = idx >> 1;          // 0..11 over fused N=3072
    const int m0 = (xcd * 2 + rr) * 256;
    const int n0 = nn * 256;
    const int tid = threadIdx.x;
    const int wave = tid >> 6, lane = tid & 63;
    const int lrow = lane & 15, lquad = lane >> 4;
    const int wr = (wave >> 2) * 128;  // 0 / 128
    const int wc = (wave & 3) * 64;    // 0 / 64 / 128 / 192

    // staging: chunk c = wave*128 + i*64 + lane (i=0,1), row=c>>2, and the
    // global col is inverse-swizzled: gcol = ((c&3) ^ (row&3)) * 8
    const int c0 = wave * 128 + lane;
    const int c1 = c0 + 64;
    const int row0 = c0 >> 2, row1 = c1 >> 2;
    const int gc0 = (((c0 & 3) ^ (row0 & 3)) * 8);
    const int gc1 = (((c1 & 3) ^ (row1 & 3)) * 8);
    const u16* gA0 = &X[(size_t)(m0 + row0) * 1024 + gc0];
    const u16* gA1 = &X[(size_t)(m0 + row1) * 1024 + gc1];
    const u16* gB0 = &WT[(size_t)(n0 + row0) * 1024 + gc0];
    const u16* gB1 = &WT[(size_t)(n0 + row1) * 1024 + gc1];
    // wave-uniform LDS bases (elements)
    const int ldsOff0 = (wave * 128) * 8;
    const int ldsOff1 = (wave * 128 + 64) * 8;

#define QSTAGE(b, kk) do { \
    async16(&As[b][ldsOff0], gA0 + (kk)); \
    async16(&As[b][ldsOff1], gA1 + (kk)); \
    async16(&Bs[b][ldsOff0], gB0 + (kk)); \
    async16(&Bs[b][ldsOff1], gB1 + (kk)); \
} while (0)

    // swizzled ds_read byte offsets (row&3 == lrow&3 for all frags)
    const int sb = (lquad * 16) ^ ((lrow & 3) << 4);

    floatx4 acc[8][4];
#pragma unroll
    for (int mt = 0; mt < 8; mt++)
#pragma unroll
        for (int nt = 0; nt < 4; nt++) acc[mt][nt] = (floatx4){0.f, 0.f, 0.f, 0.f};

#define QCOMPUTE(b) do { \
    const char* ab = (const char*)As[b]; \
    const char* bb = (const char*)Bs[b]; \
    short8 af[8], bf01[2], bf23[2]; \
    _Pragma("unroll") \
    for (int mt = 0; mt < 8; mt++) \
        af[mt] = *(const short8*)(ab + (wr + mt * 16 + lrow) * 64 + sb); \
    _Pragma("unroll") \
    for (int nt = 0; nt < 2; nt++) \
        bf01[nt] = *(const short8*)(bb + (wc + nt * 16 + lrow) * 64 + sb); \
    __builtin_amdgcn_s_setprio(1); \
    _Pragma("unroll") \
    for (int mt = 0; mt < 8; mt++) { \
        acc[mt][0] = MFMA(af[mt], bf01[0], acc[mt][0]); \
        acc[mt][1] = MFMA(af[mt], bf01[1], acc[mt][1]); \
    } \
    __builtin_amdgcn_s_setprio(0); \
    _Pragma("unroll") \
    for (int nt = 0; nt < 2; nt++) \
        bf23[nt] = *(const short8*)(bb + (wc + (nt + 2) * 16 + lrow) * 64 + sb); \
    __builtin_amdgcn_s_setprio(1); \
    _Pragma("unroll") \
    for (int mt = 0; mt < 8; mt++) { \
        acc[mt][2] = MFMA(af[mt], bf23[0], acc[mt][2]); \
        acc[mt][3] = MFMA(af[mt], bf23[1], acc[mt][3]); \
    } \
    __builtin_amdgcn_s_setprio(0); \
} while (0)

    QSTAGE(0, 0);
    QSTAGE(1, 32);
    QSTAGE(2, 64);
    for (int t = 0; t < 30; ++t) {
        asm volatile("s_waitcnt vmcnt(8)" ::: "memory");
        __builtin_amdgcn_s_barrier();
        __builtin_amdgcn_sched_barrier(0);
        if (t < 29) QSTAGE((t + 3) & 3, (t + 3) * 32);
        QCOMPUTE(t & 3);
    }
    asm volatile("s_waitcnt vmcnt(4)" ::: "memory");
    __builtin_amdgcn_s_barrier();
    __builtin_amdgcn_sched_barrier(0);
    QCOMPUTE(2);
    asm volatile("s_waitcnt vmcnt(0)" ::: "memory");
    __builtin_amdgcn_s_barrier();
    __builtin_amdgcn_sched_barrier(0);
    QCOMPUTE(3);

#undef QSTAGE
#undef QCOMPUTE

    // epilogue: mat is uniform per block (256-col tile within one 1024 mat)
    const int mat = n0 >> 10;
    const float qs = (mat == 0) ? Q_SCALE_LOG2E : 1.0f;
#pragma unroll
    for (int mt = 0; mt < 8; mt++) {
        const int gm = m0 + wr + mt * 16 + lquad * 4;
        const int b_ = gm >> 11;
        const int s  = gm & 2047;
#pragma unroll
        for (int nt = 0; nt < 4; nt++) {
            const int gn = n0 + wc + nt * 16 + lrow;
            const int h = (gn & 1023) >> 6, hd = gn & 63;
            const int bh = b_ * 16 + h;
            if (mat == 2) {
                ushort4v v;
#pragma unroll
                for (int i = 0; i < 4; i++) v[i] = f2bf(acc[mt][nt][i]);
                *(ushort4v*)&VT[((size_t)bh * 64 + hd) * 2048 + s] = v;
            } else {
                u16* dst = (mat == 0) ? Q : Kout;
#pragma unroll
                for (int i = 0; i < 4; i++)
                    dst[((size_t)bh * 2048 + s + i) * 64 + hd] = f2bf(acc[mt][nt][i] * qs);
            }
        }
    }
}

// ---------------------------------------------------------------------------
// Flash attention (causal), unchanged.
// ---------------------------------------------------------------------------
__global__ __launch_bounds__(256, 4) void attn_kernel(
    const u16* __restrict__ Q, const u16* __restrict__ Kk,
    const u16* __restrict__ VT, u16* __restrict__ ctx)
{
    __shared__ __align__(16) u16 Ks[64 * 64];
    __shared__ __align__(16) u16 Vs[64 * 64];
    __shared__ __align__(16) u16 P[4][16][80];
    const int tid = threadIdx.x, wave = tid >> 6, lane = tid & 63;
    const int lrow = lane & 15, lquad = lane >> 4;
    const float NEGINF = -__builtin_inff();

    const int bh = blockIdx.x & 31;
    const int g = blockIdx.x >> 5;
    const int qb = (g < 16) ? (31 - g) : (g - 16);
    const int ntiles = qb + 1;
    const int q0 = qb * 64 + wave * 16;

    const u16* Qb = Q  + (size_t)bh * 2048 * 64;
    const u16* Kb = Kk + (size_t)bh * 2048 * 64;
    const u16* Vb = VT + (size_t)bh * 64 * 2048;

    const short8 qf0 = *(const short8*)&Qb[(size_t)(q0 + lrow) * 64 + lquad * 8];
    const short8 qf1 = *(const short8*)&Qb[(size_t)(q0 + lrow) * 64 + 32 + lquad * 8];

    const int myq = q0 + lrow;
    float m_s = NEGINF, l_s = 0.f;
    floatx4 o[4];
#pragma unroll
    for (int i = 0; i < 4; i++) o[i] = (floatx4){0.f, 0.f, 0.f, 0.f};

    const int r0 = tid >> 3, r1 = r0 + 32;    // staging rows (0..63 across block)
    const int ce = (tid & 7) * 8;             // element col (global)
    const int cb = (tid & 7) * 16;            // byte col (LDS, pre-swizzle)

    short8 kreg0 = *(const short8*)&Kb[(size_t)r0 * 64 + ce];
    short8 kreg1 = *(const short8*)&Kb[(size_t)r1 * 64 + ce];
    short8 vreg0 = *(const short8*)&Vb[(size_t)r0 * 2048 + ce];
    short8 vreg1 = *(const short8*)&Vb[(size_t)r1 * 2048 + ce];

    for (int kt = 0; kt < ntiles; kt++) {
        __syncthreads();
        KV8(Ks, r0, cb) = kreg0;
        KV8(Ks, r1, cb) = kreg1;
        KV8(Vs, r0, cb) = vreg0;
        KV8(Vs, r1, cb) = vreg1;
        if (kt + 1 < ntiles) {
            kreg0 = *(const short8*)&Kb[(size_t)((kt + 1) * 64 + r0) * 64 + ce];
            kreg1 = *(const short8*)&Kb[(size_t)((kt + 1) * 64 + r1) * 64 + ce];
            vreg0 = *(const short8*)&Vb[(size_t)r0 * 2048 + (kt + 1) * 64 + ce];
            vreg1 = *(const short8*)&Vb[(size_t)r1 * 2048 + (kt + 1) * 64 + ce];
        }
        __syncthreads();

        floatx4 s[4];
#pragma unroll
        for (int nt = 0; nt < 4; nt++) {
            const short8 kf0 = KV8(Ks, nt * 16 + lrow, lquad * 16);
            const short8 kf1 = KV8(Ks, nt * 16 + lrow, 64 + lquad * 16);
            floatx4 a = (floatx4){0.f, 0.f, 0.f, 0.f};
            a = MFMA(kf0, qf0, a);
            a = MFMA(kf1, qf1, a);
            s[nt] = a;
        }

        if (kt == ntiles - 1) {   // causal mask, diag tile only (wave-uniform)
#pragma unroll
            for (int nt = 0; nt < 4; nt++)
#pragma unroll
                for (int i = 0; i < 4; i++)
                    if (kt * 64 + nt * 16 + lquad * 4 + i > myq) s[nt][i] = NEGINF;
        }

        float mx = NEGINF;
#pragma unroll
        for (int nt = 0; nt < 4; nt++)
            mx = fmaxf(mx, fmaxf(fmaxf(s[nt][0], s[nt][1]),
                                 fmaxf(s[nt][2], s[nt][3])));
        mx = fmaxf(mx, __shfl_xor(mx, 16));
        mx = fmaxf(mx, __shfl_xor(mx, 32));

        // defer-max (T13): only rescale when some row's max grew by >8.
        if (!__all(mx <= m_s + 8.0f)) {
            const float mnew = fmaxf(m_s, mx);
            const float alpha = fexp2(m_s - mnew);
            m_s = mnew;
            l_s *= alpha;
#pragma unroll
            for (int ht = 0; ht < 4; ht++)
#pragma unroll
                for (int i = 0; i < 4; i++) o[ht][i] *= alpha;
        }

        float sum = 0.f;
#pragma unroll
        for (int nt = 0; nt < 4; nt++)
#pragma unroll
            for (int i = 0; i < 4; i++) {
                const float pv = fexp2(s[nt][i] - m_s);
                s[nt][i] = pv;
                sum += pv;
            }
        sum += __shfl_xor(sum, 16);
        sum += __shfl_xor(sum, 32);
        l_s += sum;

#pragma unroll
        for (int nt = 0; nt < 4; nt++) {
            uint2 pk;
            pk.x = cvtpk_bf16(s[nt][0], s[nt][1]);
            pk.y = cvtpk_bf16(s[nt][2], s[nt][3]);
            *(uint2*)&P[wave][lrow][nt * 16 + lquad * 4] = pk;
        }
#pragma unroll
        for (int st = 0; st < 2; st++) {
            const short8 pf = *(const short8*)&P[wave][lrow][st * 32 + lquad * 8];
#pragma unroll
            for (int ht = 0; ht < 4; ht++) {
                const short8 vf = KV8(Vs, ht * 16 + lrow, st * 64 + lquad * 16);
                o[ht] = MFMA(vf, pf, o[ht]);
            }
        }
    }

    const int b_ = bh >> 4, h_ = bh & 15;
    const float inv_l = 1.0f / l_s;
#pragma unroll
    for (int ht = 0; ht < 4; ht++) {
        uint2 pk;
        pk.x = cvtpk_bf16(o[ht][0] * inv_l, o[ht][1] * inv_l);
        pk.y = cvtpk_bf16(o[ht][2] * inv_l, o[ht][3] * inv_l);
        *(uint2*)&ctx[((size_t)(b_ * 2048 + q0 + lrow)) * 1024 + h_ * 64 + ht * 16 + lquad * 4] = pk;
    }
}

// ---------------------------------------------------------------------------
// Output projection: ring-4 128x128 (unchanged from round 4; grid shape for
// N=1024 makes 256^2 a bad fit here).
// ---------------------------------------------------------------------------
#define RSTAGE(Abuf, Bbuf, kk) do { \
    async16((Abuf) + (wave * 128) * 8,      gA0 + (kk)); \
    async16((Abuf) + (wave * 128 + 64) * 8, gA1 + (kk)); \
    async16((Bbuf) + (wave * 128) * 8,      gB0 + (kk)); \
    async16((Bbuf) + (wave * 128 + 64) * 8, gB1 + (kk)); \
} while (0)

#define GCOMPUTE(AB, BB) do { \
    short8 af[4], bfv[4]; \
    _Pragma("unroll") \
    for (int mt = 0; mt < 4; mt++) \
        af[mt] = *(const short8*)&(AB)[(wr + mt * 16 + lrow) * 32 + lquad * 8]; \
    _Pragma("unroll") \
    for (int nt = 0; nt < 4; nt++) \
        bfv[nt] = *(const short8*)&(BB)[(wc + nt * 16 + lrow) * 32 + lquad * 8]; \
    _Pragma("unroll") \
    for (int mt = 0; mt < 4; mt++) \
        _Pragma("unroll") \
        for (int nt = 0; nt < 4; nt++) \
            acc[mt][nt] = MFMA(af[mt], bfv[nt], acc[mt][nt]); \
} while (0)

#define RING_K_LOOP() do { \
    RSTAGE(As[0], Bs[0], 0); \
    RSTAGE(As[1], Bs[1], 32); \
    RSTAGE(As[2], Bs[2], 64); \
    for (int t = 0; t < 30; ++t) { \
        asm volatile("s_waitcnt vmcnt(8)" ::: "memory"); \
        __builtin_amdgcn_s_barrier(); \
        __builtin_amdgcn_sched_barrier(0); \
        if (t < 29) RSTAGE(As[(t + 3) & 3], Bs[(t + 3) & 3], (t + 3) * 32); \
        GCOMPUTE(As[t & 3], Bs[t & 3]); \
    } \
    asm volatile("s_waitcnt vmcnt(4)" ::: "memory"); \
    __builtin_amdgcn_s_barrier(); \
    __builtin_amdgcn_sched_barrier(0); \
    GCOMPUTE(As[2], Bs[2]); \
    asm volatile("s_waitcnt vmcnt(0)" ::: "memory"); \
    __builtin_amdgcn_s_barrier(); \
    __builtin_amdgcn_sched_barrier(0); \
    GCOMPUTE(As[3], Bs[3]); \
} while (0)

__global__ __launch_bounds__(256) void gemm_out_kernel(
    const u16* __restrict__ X, const u16* __restrict__ WT,
    const float* __restrict__ bias, float* __restrict__ out)
{
    __shared__ __align__(16) u16 As[4][128 * 32];
    __shared__ __align__(16) u16 Bs[4][128 * 32];
    const int bid = blockIdx.x;
    const int xcd = bid & 7;
    const int idx = bid >> 3;          // 0..31
    const int rr  = idx >> 3;          // 0..3
    const int nn  = idx & 7;           // 0..7
    const int m0 = (xcd * 4 + rr) * 128;
    const int n0 = nn * 128;
    const int tid = threadIdx.x;
    const int wave = tid >> 6, lane = tid & 63;
    const int lrow = lane & 15, lquad = lane >> 4;
    const int wr = (wave >> 1) * 64, wc = (wave & 1) * 64;

    const int ci0 = wave * 128 + lane;
    const int ci1 = ci0 + 64;
    const int ar0 = ci0 >> 2, ac0 = (ci0 & 3) * 8;
    const int ar1 = ci1 >> 2, ac1 = (ci1 & 3) * 8;
    const u16* gA0 = &X[(size_t)(m0 + ar0) * 1024 + ac0];
    const u16* gA1 = &X[(size_t)(m0 + ar1) * 1024 + ac1];
    const u16* gB0 = &WT[(size_t)(n0 + ar0) * 1024 + ac0];
    const u16* gB1 = &WT[(size_t)(n0 + ar1) * 1024 + ac1];

    floatx4 acc[4][4];
#pragma unroll
    for (int mt = 0; mt < 4; mt++)
#pragma unroll
        for (int nt = 0; nt < 4; nt++) acc[mt][nt] = (floatx4){0.f, 0.f, 0.f, 0.f};

    RING_K_LOOP();

#pragma unroll
    for (int mt = 0; mt < 4; mt++) {
        const int gm = m0 + wr + mt * 16 + lquad * 4;
#pragma unroll
        for (int nt = 0; nt < 4; nt++) {
            const int gn = n0 + wc + nt * 16 + lrow;
            const float bv = bias[gn];
#pragma unroll
            for (int i = 0; i < 4; i++)
                out[(size_t)(gm + i) * 1024 + gn] = acc[mt][nt][i] + bv;
        }
    }
}

// ---------------------------------------------------------------------------
extern "C" void kernel_launch(void* const* d_in, const int* in_sizes, int n_in,
                              void* d_out, int out_size, void* d_ws, size_t ws_size,
                              hipStream_t stream) {
    u16* ws = (u16*)d_ws + 64;

    const size_t MB1 = 1024 * 1024;
    u16* WT   = ws;              // 4 transposed weights (bf16), contiguous [4096][1024]
    u16* Qw   = ws + 4 * MB1;    // [bh][2048][64], pre-scaled by 0.125*log2e
    u16* Kw   = ws + 8 * MB1;    // [bh][2048][64]
    u16* VTw  = ws + 12 * MB1;   // [bh][64][2048]
    u16* ctxw = ws + 16 * MB1;   // [4096][1024]
    u16* Xbf  = ws + 20 * MB1;   // x as bf16 [4096][1024]

    prep_kernel<<<dim3(32, 32, 5), dim3(32, 8), 0, stream>>>(
        (const float*)d_in[0], (const float*)d_in[1], (const float*)d_in[2],
        (const float*)d_in[3], (const float*)d_in[4], WT, Xbf);
    gemm_qkv_kernel<<<192, 512, 0, stream>>>(Xbf, WT, Qw, Kw, VTw);
    attn_kernel<<<1024, 256, 0, stream>>>(Qw, Kw, VTw, ctxw);
    gemm_out_kernel<<<256, 256, 0, stream>>>(ctxw, WT + 3 * MB1, (const float*)d_in[5], (float*)d_out);
}

// Round 6
// 180.741 us; speedup vs baseline: 1.0777x; 1.0777x over previous
//
#include <hip/hip_runtime.h>
#include <stdint.h>

typedef unsigned short u16;
typedef __attribute__((ext_vector_type(8))) short short8;
typedef __attribute__((ext_vector_type(4))) float floatx4;
typedef __attribute__((ext_vector_type(4))) u16 ushort4v;

typedef __attribute__((address_space(1))) const uint32_t gu32;
typedef __attribute__((address_space(3))) uint32_t lu32;

#define MFMA(a, b, c) __builtin_amdgcn_mfma_f32_16x16x32_bf16((a), (b), (c), 0, 0, 0)

__device__ __forceinline__ u16 f2bf(float f) {
    union { float f; uint32_t u; } x; x.f = f;
    uint32_t u = x.u;
    u += 0x7fffu + ((u >> 16) & 1u);
    return (u16)(u >> 16);
}

// packed f32x2 -> bf16x2 (RNE), single instruction (T12 primitive)
__device__ __forceinline__ uint32_t cvtpk_bf16(float lo, float hi) {
    uint32_t r;
    asm("v_cvt_pk_bf16_f32 %0, %1, %2" : "=v"(r) : "v"(lo), "v"(hi));
    return r;
}

// hardware exp2 (v_exp_f32 IS exp2)
__device__ __forceinline__ float fexp2(float x) {
#if defined(__has_builtin)
#if __has_builtin(__builtin_amdgcn_exp2f)
    return __builtin_amdgcn_exp2f(x);
#else
    return exp2f(x);
#endif
#else
    return exp2f(x);
#endif
}

// async global->LDS DMA, 16B per lane; lds base must be wave-uniform,
// HW scatters to base + lane*16 (m104/m108).
__device__ __forceinline__ void async16(u16* lds, const u16* g) {
    __builtin_amdgcn_global_load_lds((gu32*)g, (lu32*)lds, 16, 0, 0);
}

// K/V LDS tiles (attn): [64 rows][128 B], XOR-swizzled: byte ^= (row&7)<<4.
#define KV8(buf, row, byteInRow) \
    (*(short8*)((char*)(buf) + (((row) << 7) + ((byteInRow) ^ (((row) & 7) << 4)))))

// 0.125 (1/sqrt(64)) * log2(e): folded into Q so softmax runs in exp2 domain.
#define Q_SCALE_LOG2E 0.18033688011112042f

// ---------------------------------------------------------------------------
// prep: z=0..3 transpose W_z [k][n] fp32 -> WT [n][k] bf16; z=4 convert x.
// ---------------------------------------------------------------------------
__global__ __launch_bounds__(256) void prep_kernel(
    const float* __restrict__ x,
    const float* __restrict__ W0, const float* __restrict__ W1,
    const float* __restrict__ W2, const float* __restrict__ W3,
    u16* __restrict__ WT, u16* __restrict__ Xbf)
{
    const int z = blockIdx.z;
    const int tx = threadIdx.x, ty = threadIdx.y;
    if (z == 4) {
        const int bid = blockIdx.y * 32 + blockIdx.x;
        const int t = ty * 32 + tx;
        const size_t base = ((size_t)bid * 256 + t) * 16;
        const float* xf = x + base;
        short8 v0, v1;
#pragma unroll
        for (int j = 0; j < 8; j++) v0[j] = (short)f2bf(xf[j]);
#pragma unroll
        for (int j = 0; j < 8; j++) v1[j] = (short)f2bf(xf[8 + j]);
        *(short8*)&Xbf[base] = v0;
        *(short8*)&Xbf[base + 8] = v1;
        return;
    }
    __shared__ u16 tile[32][33];
    const float* W = (z == 0) ? W0 : (z == 1) ? W1 : (z == 2) ? W2 : W3;
    u16* dst = WT + (size_t)z * 1024 * 1024;
    const int n0 = blockIdx.x * 32, k0 = blockIdx.y * 32;
#pragma unroll
    for (int i = 0; i < 4; i++)
        tile[ty + i * 8][tx] = f2bf(W[(size_t)(k0 + ty + i * 8) * 1024 + n0 + tx]);
    __syncthreads();
#pragma unroll
    for (int i = 0; i < 4; i++)
        dst[(size_t)(n0 + ty + i * 8) * 1024 + k0 + tx] = tile[tx][ty + i * 8];
}

// ---------------------------------------------------------------------------
// GEMM core, BK=64 / 128x128 tile / 4 waves / single 32-KB LDS buffer.
// Theory: per-K-step cost is ~fixed (duration invariant to all schedule
// changes, r1-r5) -> halve step count, double work per step, and kill the
// LDS bank conflict that every previous round carried.
//
// LDS tiles A[128][64], B[128][64] (128-B rows). Swizzle (G4/T2, rule 21):
//   logical granule g = k/8 (0..7) of row r stored at granule g ^ (r&7);
//   gload_lds dest stays LINEAR (chunk c = r*8 + phys), global SOURCE col
//   is inverse-swizzled; ds_read applies the same XOR.
// Staging: chunk c_i = tid + 256*i (i=0..3) per matrix:
//   row = (tid>>3) + 32*i, phys granule p = tid&7 (const),
//   src col = (p ^ ((tid>>3)&7)) * 8 (const across i since 32*i % 8 == 0).
// Compute: 2 K-slices (ks=0,1), each 8 ds_read_b128 + 16 MFMA.
// ---------------------------------------------------------------------------
#define GSTAGE64(buf, gptr, kk) do { \
    _Pragma("unroll") \
    for (int i_ = 0; i_ < 4; i_++) \
        async16((buf) + wave * 512 + i_ * 2048, (gptr) + (kk) + (size_t)i_ * 32 * 1024); \
} while (0)

// frag read: row = base + fr*16 + lrow (row&7 == lrow&7); granule g = ks*4+lquad
#define GFRAG64(buf, base, ks, fr) \
    (*(const short8*)&(buf)[((base) + (fr) * 16 + lrow) * 64 + ((((ks) * 4 + lquad) ^ (lrow & 7)) * 8)])

#define GCOMPUTE64() do { \
    _Pragma("unroll") \
    for (int ks = 0; ks < 2; ks++) { \
        short8 af[4], bfv[4]; \
        _Pragma("unroll") \
        for (int mt = 0; mt < 4; mt++) af[mt] = GFRAG64(As, wr, ks, mt); \
        _Pragma("unroll") \
        for (int nt = 0; nt < 4; nt++) bfv[nt] = GFRAG64(Bs, wc, ks, nt); \
        _Pragma("unroll") \
        for (int mt = 0; mt < 4; mt++) \
            _Pragma("unroll") \
            for (int nt = 0; nt < 4; nt++) \
                acc[mt][nt] = MFMA(af[mt], bfv[nt], acc[mt][nt]); \
    } \
} while (0)

#define GEMM_K_LOOP64() do { \
    for (int kk = 0; kk < 1024; kk += 64) { \
        __syncthreads(); \
        GSTAGE64(As, gA, kk); \
        GSTAGE64(Bs, gB, kk); \
        __syncthreads(); \
        GCOMPUTE64(); \
    } \
} while (0)

// ---------------------------------------------------------------------------
// QKV GEMM: 768 blocks (xcd-striped), BK=64 structure above.
// Q outputs pre-scaled by 0.125*log2e (softmax runs in exp2 domain).
// ---------------------------------------------------------------------------
__global__ __launch_bounds__(256) void gemm_qkv_kernel(
    const u16* __restrict__ X, const u16* __restrict__ WT,
    u16* __restrict__ Q, u16* __restrict__ Kout, u16* __restrict__ VT)
{
    __shared__ __align__(16) u16 As[128 * 64];
    __shared__ __align__(16) u16 Bs[128 * 64];
    const int bid = blockIdx.x;
    const int xcd = bid & 7;
    const int idx = bid >> 3;          // 0..95
    const int mat = idx >> 5;          // 0..2
    const int rr  = (idx >> 3) & 3;    // 0..3
    const int nn  = idx & 7;           // 0..7
    const int m0 = (xcd * 4 + rr) * 128;
    const int n0 = nn * 128;
    const u16* BW = WT + (size_t)mat * 1024 * 1024;
    const int tid = threadIdx.x;
    const int wave = tid >> 6, lane = tid & 63;
    const int lrow = lane & 15, lquad = lane >> 4;
    const int wr = (wave >> 1) * 64, wc = (wave & 1) * 64;

    const int stg_r = tid >> 3;                                  // 0..31
    const int stg_c = ((tid & 7) ^ ((tid >> 3) & 7)) * 8;        // inv-swizzled col
    const u16* gA = &X[(size_t)(m0 + stg_r) * 1024 + stg_c];
    const u16* gB = &BW[(size_t)(n0 + stg_r) * 1024 + stg_c];

    floatx4 acc[4][4];
#pragma unroll
    for (int mt = 0; mt < 4; mt++)
#pragma unroll
        for (int nt = 0; nt < 4; nt++) acc[mt][nt] = (floatx4){0.f, 0.f, 0.f, 0.f};

    GEMM_K_LOOP64();

    const float qs = (mat == 0) ? Q_SCALE_LOG2E : 1.0f;
#pragma unroll
    for (int mt = 0; mt < 4; mt++) {
        const int gm = m0 + wr + mt * 16 + lquad * 4;
        const int b_ = gm >> 11;
        const int s  = gm & 2047;
#pragma unroll
        for (int nt = 0; nt < 4; nt++) {
            const int gn = n0 + wc + nt * 16 + lrow;
            const int h = gn >> 6, hd = gn & 63;
            const int bh = b_ * 16 + h;
            if (mat == 2) {
                ushort4v v;
#pragma unroll
                for (int i = 0; i < 4; i++) v[i] = f2bf(acc[mt][nt][i]);
                *(ushort4v*)&VT[((size_t)bh * 64 + hd) * 2048 + s] = v;
            } else {
                u16* dst = (mat == 0) ? Q : Kout;
#pragma unroll
                for (int i = 0; i < 4; i++)
                    dst[((size_t)bh * 2048 + s + i) * 64 + hd] = f2bf(acc[mt][nt][i] * qs);
            }
        }
    }
}

// ---------------------------------------------------------------------------
// Flash attention (causal), unchanged.
// ---------------------------------------------------------------------------
__global__ __launch_bounds__(256, 4) void attn_kernel(
    const u16* __restrict__ Q, const u16* __restrict__ Kk,
    const u16* __restrict__ VT, u16* __restrict__ ctx)
{
    __shared__ __align__(16) u16 Ks[64 * 64];
    __shared__ __align__(16) u16 Vs[64 * 64];
    __shared__ __align__(16) u16 P[4][16][80];
    const int tid = threadIdx.x, wave = tid >> 6, lane = tid & 63;
    const int lrow = lane & 15, lquad = lane >> 4;
    const float NEGINF = -__builtin_inff();

    const int bh = blockIdx.x & 31;
    const int g = blockIdx.x >> 5;
    const int qb = (g < 16) ? (31 - g) : (g - 16);
    const int ntiles = qb + 1;
    const int q0 = qb * 64 + wave * 16;

    const u16* Qb = Q  + (size_t)bh * 2048 * 64;
    const u16* Kb = Kk + (size_t)bh * 2048 * 64;
    const u16* Vb = VT + (size_t)bh * 64 * 2048;

    const short8 qf0 = *(const short8*)&Qb[(size_t)(q0 + lrow) * 64 + lquad * 8];
    const short8 qf1 = *(const short8*)&Qb[(size_t)(q0 + lrow) * 64 + 32 + lquad * 8];

    const int myq = q0 + lrow;
    float m_s = NEGINF, l_s = 0.f;
    floatx4 o[4];
#pragma unroll
    for (int i = 0; i < 4; i++) o[i] = (floatx4){0.f, 0.f, 0.f, 0.f};

    const int r0 = tid >> 3, r1 = r0 + 32;    // staging rows (0..63 across block)
    const int ce = (tid & 7) * 8;             // element col (global)
    const int cb = (tid & 7) * 16;            // byte col (LDS, pre-swizzle)

    short8 kreg0 = *(const short8*)&Kb[(size_t)r0 * 64 + ce];
    short8 kreg1 = *(const short8*)&Kb[(size_t)r1 * 64 + ce];
    short8 vreg0 = *(const short8*)&Vb[(size_t)r0 * 2048 + ce];
    short8 vreg1 = *(const short8*)&Vb[(size_t)r1 * 2048 + ce];

    for (int kt = 0; kt < ntiles; kt++) {
        __syncthreads();
        KV8(Ks, r0, cb) = kreg0;
        KV8(Ks, r1, cb) = kreg1;
        KV8(Vs, r0, cb) = vreg0;
        KV8(Vs, r1, cb) = vreg1;
        if (kt + 1 < ntiles) {
            kreg0 = *(const short8*)&Kb[(size_t)((kt + 1) * 64 + r0) * 64 + ce];
            kreg1 = *(const short8*)&Kb[(size_t)((kt + 1) * 64 + r1) * 64 + ce];
            vreg0 = *(const short8*)&Vb[(size_t)r0 * 2048 + (kt + 1) * 64 + ce];
            vreg1 = *(const short8*)&Vb[(size_t)r1 * 2048 + (kt + 1) * 64 + ce];
        }
        __syncthreads();

        floatx4 s[4];
#pragma unroll
        for (int nt = 0; nt < 4; nt++) {
            const short8 kf0 = KV8(Ks, nt * 16 + lrow, lquad * 16);
            const short8 kf1 = KV8(Ks, nt * 16 + lrow, 64 + lquad * 16);
            floatx4 a = (floatx4){0.f, 0.f, 0.f, 0.f};
            a = MFMA(kf0, qf0, a);
            a = MFMA(kf1, qf1, a);
            s[nt] = a;
        }

        if (kt == ntiles - 1) {   // causal mask, diag tile only (wave-uniform)
#pragma unroll
            for (int nt = 0; nt < 4; nt++)
#pragma unroll
                for (int i = 0; i < 4; i++)
                    if (kt * 64 + nt * 16 + lquad * 4 + i > myq) s[nt][i] = NEGINF;
        }

        float mx = NEGINF;
#pragma unroll
        for (int nt = 0; nt < 4; nt++)
            mx = fmaxf(mx, fmaxf(fmaxf(s[nt][0], s[nt][1]),
                                 fmaxf(s[nt][2], s[nt][3])));
        mx = fmaxf(mx, __shfl_xor(mx, 16));
        mx = fmaxf(mx, __shfl_xor(mx, 32));

        // defer-max (T13): only rescale when some row's max grew by >8.
        if (!__all(mx <= m_s + 8.0f)) {
            const float mnew = fmaxf(m_s, mx);
            const float alpha = fexp2(m_s - mnew);
            m_s = mnew;
            l_s *= alpha;
#pragma unroll
            for (int ht = 0; ht < 4; ht++)
#pragma unroll
                for (int i = 0; i < 4; i++) o[ht][i] *= alpha;
        }

        float sum = 0.f;
#pragma unroll
        for (int nt = 0; nt < 4; nt++)
#pragma unroll
            for (int i = 0; i < 4; i++) {
                const float pv = fexp2(s[nt][i] - m_s);
                s[nt][i] = pv;
                sum += pv;
            }
        sum += __shfl_xor(sum, 16);
        sum += __shfl_xor(sum, 32);
        l_s += sum;

#pragma unroll
        for (int nt = 0; nt < 4; nt++) {
            uint2 pk;
            pk.x = cvtpk_bf16(s[nt][0], s[nt][1]);
            pk.y = cvtpk_bf16(s[nt][2], s[nt][3]);
            *(uint2*)&P[wave][lrow][nt * 16 + lquad * 4] = pk;
        }
#pragma unroll
        for (int st = 0; st < 2; st++) {
            const short8 pf = *(const short8*)&P[wave][lrow][st * 32 + lquad * 8];
#pragma unroll
            for (int ht = 0; ht < 4; ht++) {
                const short8 vf = KV8(Vs, ht * 16 + lrow, st * 64 + lquad * 16);
                o[ht] = MFMA(vf, pf, o[ht]);
            }
        }
    }

    const int b_ = bh >> 4, h_ = bh & 15;
    const float inv_l = 1.0f / l_s;
#pragma unroll
    for (int ht = 0; ht < 4; ht++) {
        uint2 pk;
        pk.x = cvtpk_bf16(o[ht][0] * inv_l, o[ht][1] * inv_l);
        pk.y = cvtpk_bf16(o[ht][2] * inv_l, o[ht][3] * inv_l);
        *(uint2*)&ctx[((size_t)(b_ * 2048 + q0 + lrow)) * 1024 + h_ * 64 + ht * 16 + lquad * 4] = pk;
    }
}

// ---------------------------------------------------------------------------
// Output projection: same BK=64 structure; epilogue adds bias, stores fp32.
// ---------------------------------------------------------------------------
__global__ __launch_bounds__(256) void gemm_out_kernel(
    const u16* __restrict__ X, const u16* __restrict__ WT,
    const float* __restrict__ bias, float* __restrict__ out)
{
    __shared__ __align__(16) u16 As[128 * 64];
    __shared__ __align__(16) u16 Bs[128 * 64];
    const int bid = blockIdx.x;
    const int xcd = bid & 7;
    const int idx = bid >> 3;          // 0..31
    const int rr  = idx >> 3;          // 0..3
    const int nn  = idx & 7;           // 0..7
    const int m0 = (xcd * 4 + rr) * 128;
    const int n0 = nn * 128;
    const int tid = threadIdx.x;
    const int wave = tid >> 6, lane = tid & 63;
    const int lrow = lane & 15, lquad = lane >> 4;
    const int wr = (wave >> 1) * 64, wc = (wave & 1) * 64;

    const int stg_r = tid >> 3;
    const int stg_c = ((tid & 7) ^ ((tid >> 3) & 7)) * 8;
    const u16* gA = &X[(size_t)(m0 + stg_r) * 1024 + stg_c];
    const u16* gB = &WT[(size_t)(n0 + stg_r) * 1024 + stg_c];

    floatx4 acc[4][4];
#pragma unroll
    for (int mt = 0; mt < 4; mt++)
#pragma unroll
        for (int nt = 0; nt < 4; nt++) acc[mt][nt] = (floatx4){0.f, 0.f, 0.f, 0.f};

    GEMM_K_LOOP64();

#pragma unroll
    for (int mt = 0; mt < 4; mt++) {
        const int gm = m0 + wr + mt * 16 + lquad * 4;
#pragma unroll
        for (int nt = 0; nt < 4; nt++) {
            const int gn = n0 + wc + nt * 16 + lrow;
            const float bv = bias[gn];
#pragma unroll
            for (int i = 0; i < 4; i++)
                out[(size_t)(gm + i) * 1024 + gn] = acc[mt][nt][i] + bv;
        }
    }
}

// ---------------------------------------------------------------------------
extern "C" void kernel_launch(void* const* d_in, const int* in_sizes, int n_in,
                              void* d_out, int out_size, void* d_ws, size_t ws_size,
                              hipStream_t stream) {
    u16* ws = (u16*)d_ws + 64;

    const size_t MB1 = 1024 * 1024;
    u16* WT   = ws;              // 4 transposed weights (bf16)
    u16* Qw   = ws + 4 * MB1;    // [bh][2048][64], pre-scaled by 0.125*log2e
    u16* Kw   = ws + 8 * MB1;    // [bh][2048][64]
    u16* VTw  = ws + 12 * MB1;   // [bh][64][2048]
    u16* ctxw = ws + 16 * MB1;   // [4096][1024]
    u16* Xbf  = ws + 20 * MB1;   // x as bf16 [4096][1024]

    prep_kernel<<<dim3(32, 32, 5), dim3(32, 8), 0, stream>>>(
        (const float*)d_in[0], (const float*)d_in[1], (const float*)d_in[2],
        (const float*)d_in[3], (const float*)d_in[4], WT, Xbf);
    gemm_qkv_kernel<<<768, 256, 0, stream>>>(Xbf, WT, Qw, Kw, VTw);
    attn_kernel<<<1024, 256, 0, stream>>>(Qw, Kw, VTw, ctxw);
    gemm_out_kernel<<<256, 256, 0, stream>>>(ctxw, WT + 3 * MB1, (const float*)d_in[5], (float*)d_out);
}